// Round 6
// baseline (387.334 us; speedup 1.0000x reference)
//
#include <hip/hip_runtime.h>
#include <hip/hip_bf16.h>
#include <math.h>

#define N_AC  8192
#define N_BC  8192
#define T_K   52
#define T_PAD 64

#define KSPLIT 32                 // K-way split; one 256-wide k-range per WG
#define KSEG   (N_BC / KSPLIT)    // 256 k per WG (and per wave)
#define NKB    (KSEG / 32)        // 8 k-steps (kblocks) per segment

typedef __bf16 bf16x8 __attribute__((ext_vector_type(8)));
typedef float  f32x4  __attribute__((ext_vector_type(4)));

// ---------------------------------------------------------------------------
// Pack x into MFMA B-fragment order (bf16, t zero-padded to 64):
// group g = kblock*4 + nt  (kblock = k/32, 256 of them; nt = t-tile, 4)
// within group: lane (quad=lane>>4, l15=lane&15) holds 8 bf16 =
//   x[b = kblock*32 + quad*8 + j][t = nt*16 + l15],  j = 0..7
// ---------------------------------------------------------------------------
__global__ void bpack_kernel(const float* __restrict__ x, __bf16* __restrict__ Bp) {
    int gid   = blockIdx.x * blockDim.x + threadIdx.x;  // 65536 threads
    int lane  = gid & 63;
    int group = gid >> 6;            // 0..1023
    int kblock = group >> 2;
    int nt     = group & 3;
    int quad = lane >> 4;
    int l15  = lane & 15;
    int t  = nt * 16 + l15;
    int b0 = kblock * 32 + quad * 8;
    bf16x8 v;
    #pragma unroll
    for (int j = 0; j < 8; ++j) {
        float f = (t < T_K) ? x[(b0 + j) * T_K + t] : 0.0f;
        v[j] = (__bf16)f;
    }
    *(bf16x8*)(Bp + (size_t)group * 512 + lane * 8) = v;
}

// ---------------------------------------------------------------------------
// GEMM: grid (128, 32) x 256 thr. WG = 64 AC rows x 256-wide k-segment.
// Stage the WG's packed-B slice (32 KB) into LDS once (single barrier).
// Then, per wave (16 rows), prefetch the wave's ENTIRE 16 KB W slice into
// registers (16 float4/lane, in-order retire -> perfect vmcnt pipelining),
// and consume: per k-step cvt fp32->bf16 A-frag + 4 ds_read_b128 B-frags
// (lgkmcnt domain, decoupled from the W vmcnt stream) + 4 MFMAs.
//
// Fragment layouts (verified rounds 1-5):
//   A: lane holds A[m = lane&15][k = (lane>>4)*8 + j]
//   B: lane holds B[k = (lane>>4)*8 + j][n = lane&15]
//   D: lane holds D[row = (lane>>4)*4 + r][col = lane&15]
// ---------------------------------------------------------------------------
__global__ __launch_bounds__(256, 4) void ac_gemm_kernel(
    const float*  __restrict__ W,        // (N_AC, N_BC) fp32
    const __bf16* __restrict__ Bp,       // packed B (1 MB)
    const float*  __restrict__ kern,     // (N_AC, T_K) fp32
    float*        __restrict__ partials) // (KSPLIT, N_AC)
{
    const int tid  = threadIdx.x;
    const int lane = tid & 63;
    const int wave = tid >> 6;
    const int quad = lane >> 4;
    const int l15  = lane & 15;
    const int a0   = blockIdx.x * 64 + wave * 16;   // this wave's 16 rows
    const int ksub = blockIdx.y;
    const int kbeg = ksub * KSEG;

    // ---- stage this WG's B slice: 32 groups x 1 KB = 32 KB ----
    __shared__ __bf16 Bs[NKB * 4 * 512];
    {
        const __bf16* src = Bp + (size_t)(ksub * NKB * 4) * 512;
        #pragma unroll
        for (int j = 0; j < 8; ++j)
            *(bf16x8*)(Bs + (j * 256 + tid) * 8) =
                *(const bf16x8*)(src + (j * 256 + tid) * 8);
    }
    __syncthreads();   // only barrier in the kernel

    // ---- prefetch the wave's entire W slice into registers ----
    // k-step s uses pre[2s] (floats koff..+3) and pre[2s+1] (koff+4..+7)
    const float* wrow = W + (size_t)(a0 + l15) * N_BC + kbeg + quad * 8;
    float4 pre[2 * NKB];
    #pragma unroll
    for (int s = 0; s < NKB; ++s) {
        pre[2 * s]     = *(const float4*)(wrow + s * 32);
        pre[2 * s + 1] = *(const float4*)(wrow + s * 32 + 4);
    }

    f32x4 acc[4] = {};   // 4 t-tiles: [0,16),[16,32),[32,48),[48,64)

    #pragma unroll
    for (int s = 0; s < NKB; ++s) {
        bf16x8 af;
        af[0] = (__bf16)pre[2*s].x;   af[1] = (__bf16)pre[2*s].y;
        af[2] = (__bf16)pre[2*s].z;   af[3] = (__bf16)pre[2*s].w;
        af[4] = (__bf16)pre[2*s+1].x; af[5] = (__bf16)pre[2*s+1].y;
        af[6] = (__bf16)pre[2*s+1].z; af[7] = (__bf16)pre[2*s+1].w;
        #pragma unroll
        for (int nt = 0; nt < 4; ++nt) {
            bf16x8 bf = *(const bf16x8*)(Bs + ((s * 4 + nt) * 512 + lane * 8));
            acc[nt] = __builtin_amdgcn_mfma_f32_16x16x32_bf16(af, bf, acc[nt], 0, 0, 0);
        }
    }

    // ---- temporal weighting: p[r] = sum_t kern[row, t] * y[row, t] ----
    float p[4] = {0.f, 0.f, 0.f, 0.f};
    #pragma unroll
    for (int nt = 0; nt < 4; ++nt) {
        int t = nt * 16 + l15;
        if (t < T_K) {
            #pragma unroll
            for (int r = 0; r < 4; ++r) {
                int grow = a0 + quad * 4 + r;
                p[r] += acc[nt][r] * kern[grow * T_K + t];
            }
        }
    }
    #pragma unroll
    for (int m = 1; m <= 8; m <<= 1) {
        #pragma unroll
        for (int r = 0; r < 4; ++r) p[r] += __shfl_xor(p[r], m);
    }

    if (l15 == 0) {
        #pragma unroll
        for (int r = 0; r < 4; ++r)
            partials[ksub * N_AC + a0 + quad * 4 + r] = p[r];
    }
}

// ---------------------------------------------------------------------------
// Final: reduce K-split partials, fused sigmoid
// ---------------------------------------------------------------------------
__global__ void ac_final_kernel(const float* __restrict__ partials,
                                const float* __restrict__ slope,
                                const float* __restrict__ offs,
                                float* __restrict__ out) {
    int a = blockIdx.x * blockDim.x + threadIdx.x;
    if (a >= N_AC) return;
    float s = 0.f;
    #pragma unroll
    for (int ks = 0; ks < KSPLIT; ++ks) s += partials[ks * N_AC + a];
    float z = slope[a] * (s - offs[a]);
    out[a] = 1.0f / (1.0f + __expf(-z));
}

extern "C" void kernel_launch(void* const* d_in, const int* in_sizes, int n_in,
                              void* d_out, int out_size, void* d_ws, size_t ws_size,
                              hipStream_t stream) {
    const float* x     = (const float*)d_in[0];  // (N_BC, T_K)
    const float* W     = (const float*)d_in[1];  // (N_AC, N_BC)
    const float* kern  = (const float*)d_in[2];  // (N_AC, T_K)
    const float* slope = (const float*)d_in[3];  // (N_AC,)
    const float* offs  = (const float*)d_in[4];  // (N_AC,)
    float* out = (float*)d_out;

    __bf16* Bp      = (__bf16*)d_ws;                                   // 1 MB
    float* partials = (float*)((char*)d_ws + (size_t)1024 * 512 * sizeof(__bf16));

    bpack_kernel<<<dim3(65536 / 256), dim3(256), 0, stream>>>(x, Bp);
    ac_gemm_kernel<<<dim3(N_AC / 64, KSPLIT), dim3(256), 0, stream>>>(
        W, Bp, kern, partials);
    ac_final_kernel<<<dim3(N_AC / 256), dim3(256), 0, stream>>>(
        partials, slope, offs, out);
}